// Round 5
// baseline (413.070 us; speedup 1.0000x reference)
//
#include <hip/hip_runtime.h>

// TangentSpaceLoss: loss = (1/B^2) sum_ij softmax_j(E E^T)_ij * ||v_i - v_j||^2
// B=8192, G=512, D=64.
//
// R18: MEASUREMENT ROUND. Falsified so far for k_mega's constant ~70us:
// traffic (R14/R16: FETCH 35->13MB, dur 0-delta), source pipelining (R15:
// codegen-neutral), occupancy (R17: 26->36%, dur WORSE 70->83). G-vs-S split
// never measured; rocprof top-5 shows only the longest kernel -> add ONE
// ablation kernel guaranteed to surface: k_mega_g = G phase only, REP=5
// (5G >= 85us > 70us since G MFMA floor ~17us). Laundered per-rep addresses
// (asm "+v") defeat load CSE; asm sink keeps gacc live (rule #17). Real
// pipeline (R16-exact 135us config) unchanged -> result still correct.
// Decode: top5_dur/5 = G. G>=40 -> attack G (LDS staging via global_load_lds,
// lane-linear VF8). G~25-30 -> attack S epilogue (exp2, LDS-atomic reduce).
// G<=20 -> G at floor, all slack is S.
//   G: fp8 e4m3 MFMA K=512 (VF8 frag-linear, 16B/lane wave-loads, no LDS
//      staging, no barriers in the loop)
//   S: fp16 MFMA (EFh frag-linear, B-frags hoisted), fused epilogue with
//      ballot-skip; LDS-plane cross-wave combine (R8-verified).
// Selection: s > min(ne_i,ne_j)-32 (safe superset). Softmax shift ne_i;
// diagonal w=1, wd=0 -> Z preinit 1.
//
// VF8: [rt 512][c 8][m 16][q 4][kc 2][8B]; lane (m,quad) reads 16B at
// m*64+quad*16 (bytes 0-7 = K-chunk kc0, 8-15 = kc1).
// EFh: [rt 512][kc 2][m 16][k' 32] halfs.

#define SEL_T 32.0f

typedef _Float16 half8 __attribute__((ext_vector_type(8)));
typedef float    f32x4 __attribute__((ext_vector_type(4)));
typedef long     l2t   __attribute__((ext_vector_type(2)));

#define MFMA16(a, b, c) __builtin_amdgcn_mfma_f32_16x16x32_f16(a, b, c, 0, 0, 0)
#define MFMA8(a, b, c)  __builtin_amdgcn_mfma_f32_16x16x32_fp8_fp8(a, b, c, 0, 0, 0)

// Shared super-tile decode: blk0 -> (bx<=by), XCD-windowed.
__device__ __forceinline__ void st_decode(int blk0, int& bx, int& by) {
    int g = (blk0 & 7) * 260 + (blk0 >> 3);
    int SY = 0;
#pragma unroll
    for (int s = 1; s < 8; ++s) if (32 * s * s + 4 * s <= g) SY = s;
    int rr = g - (32 * SY * SY + 4 * SY);
    if (rr < 64 * SY) {                         // off-diagonal ST (full 8x8)
        int SX = rr >> 6, t = rr & 63;
        bx = (SX << 3) + (t & 7);
        by = (SY << 3) + (t >> 3);
    } else {                                    // diagonal ST (36 blocks)
        int t = rr - 64 * SY;
        int ly = 0;
#pragma unroll
        for (int s = 1; s < 8; ++s) if (s * (s + 1) / 2 <= t) ly = s;
        int lx = t - ly * (ly + 1) / 2;
        bx = (SY << 3) + lx;
        by = (SY << 3) + ly;
    }
}

// ---------------- K1: norms + fp8 V + fp16 E layouts + Z/num init -------
__global__ __launch_bounds__(256) void k_prep(
    const float* __restrict__ V, const float* __restrict__ E,
    float* __restrict__ n, float* __restrict__ ne,
    float* __restrict__ Z, float* __restrict__ num,
    unsigned char* __restrict__ VF8, _Float16* __restrict__ EFh,
    unsigned* __restrict__ cnt) {
    int rt = blockIdx.x;                       // 512 row-tiles of 16 rows
    int tid = threadIdx.x, wave = tid >> 6, lane = tid & 63;
    if (rt == 0 && tid == 0) *cnt = 0;
    int m = lane >> 2, q = lane & 3;
    int row = rt * 16 + m;
    const float* vr = V + (size_t)row * 512;
    float sn = 0.f;
#pragma unroll
    for (int it = 0; it < 2; ++it) {
        int c = wave + it * 4;                 // K-chunk of 64
        const float4* p0 = (const float4*)(vr + c * 64 + q * 8);
        const float4* p1 = (const float4*)(vr + c * 64 + 32 + q * 8);
        float4 a0 = p0[0], a1 = p0[1], b0 = p1[0], b1 = p1[1];
        int w0 = 0, w1 = 0, w2 = 0, w3 = 0;
        w0 = __builtin_amdgcn_cvt_pk_fp8_f32(a0.x, a0.y, w0, false);
        w0 = __builtin_amdgcn_cvt_pk_fp8_f32(a0.z, a0.w, w0, true);
        w1 = __builtin_amdgcn_cvt_pk_fp8_f32(a1.x, a1.y, w1, false);
        w1 = __builtin_amdgcn_cvt_pk_fp8_f32(a1.z, a1.w, w1, true);
        w2 = __builtin_amdgcn_cvt_pk_fp8_f32(b0.x, b0.y, w2, false);
        w2 = __builtin_amdgcn_cvt_pk_fp8_f32(b0.z, b0.w, w2, true);
        w3 = __builtin_amdgcn_cvt_pk_fp8_f32(b1.x, b1.y, w3, false);
        w3 = __builtin_amdgcn_cvt_pk_fp8_f32(b1.z, b1.w, w3, true);
        uint4 o;
        o.x = (unsigned)w0; o.y = (unsigned)w1;
        o.z = (unsigned)w2; o.w = (unsigned)w3;
        *(uint4*)(VF8 + (((size_t)rt * 8 + c) << 10) + lane * 16) = o;
        sn += a0.x*a0.x + a0.y*a0.y + a0.z*a0.z + a0.w*a0.w
            + a1.x*a1.x + a1.y*a1.y + a1.z*a1.z + a1.w*a1.w
            + b0.x*b0.x + b0.y*b0.y + b0.z*b0.z + b0.w*b0.w
            + b1.x*b1.x + b1.y*b1.y + b1.z*b1.z + b1.w*b1.w;
    }
    __shared__ float sred[4][64];
    sred[wave][lane] = sn;
    __syncthreads();
    if (tid < 16) {
        float s = 0.f;
#pragma unroll
        for (int w = 0; w < 4; ++w)
#pragma unroll
            for (int qq = 0; qq < 4; ++qq) s += sred[w][tid * 4 + qq];
        int rr = rt * 16 + tid;
        n[rr] = s;
        Z[rr] = 1.0f;                          // diagonal w=1, wd=0
        num[rr] = 0.0f;
    }
    // E: threads 0..127: rl = t>>3, u = t&7, k in [u*8, u*8+8)
    if (tid < 128) {
        int rl = tid >> 3, u = tid & 7;
        int erow = rt * 16 + rl;
        const float4* er = (const float4*)(E + (size_t)erow * 64);
        float4 x0 = er[u * 2], x1 = er[u * 2 + 1];
        float xf[8] = {x0.x, x0.y, x0.z, x0.w, x1.x, x1.y, x1.z, x1.w};
        half8 h;
        float se = 0.f;
#pragma unroll
        for (int k = 0; k < 8; ++k) {
            h[k] = (_Float16)xf[k];
            se += xf[k] * xf[k];
        }
        int kc = u >> 2, qq = u & 3;
        *(half8*)(EFh + ((size_t)rt * 2 + kc) * 512 + rl * 32 + qq * 8) = h;
        se += __shfl_xor(se, 1, 64);
        se += __shfl_xor(se, 2, 64);
        se += __shfl_xor(se, 4, 64);
        if (u == 0) ne[erow] = se;
    }
}

// ---------------- K2: zero-LDS gather tile kernel (R16-exact) -----------
// 256 thr = 4 waves in 2x2 grid; wave tile 64x64 = 4x4 MFMA tiles.
__global__ __launch_bounds__(256, 3) void k_mega(
    const unsigned char* __restrict__ VF8, const _Float16* __restrict__ EFh,
    const float* __restrict__ ne, const float* __restrict__ nrm,
    float* __restrict__ Z, float* __restrict__ num) {
    int bx, by;
    st_decode(blockIdx.x, bx, by);
    int i0 = bx << 7, j0 = by << 7;
    bool diag = (bx == by);

    __shared__ float sNeI[128], sNeJ[128], sNI[128], sNJ[128];
    __shared__ float scr[1024];

    int tid = threadIdx.x;
    if (tid < 128) { sNeI[tid] = ne[i0 + tid]; sNI[tid] = nrm[i0 + tid]; }
    else { sNeJ[tid - 128] = ne[j0 + tid - 128]; sNJ[tid - 128] = nrm[j0 + tid - 128]; }
    __syncthreads();

    int wave = tid >> 6, lane = tid & 63;
    int m = lane & 15, quad = lane >> 4;
    int wi = wave & 1, wj = wave >> 1;
    int rtA = (i0 >> 4) + wi * 4;            // + im
    int rtB = (j0 >> 4) + wj * 4;            // + jn
    size_t loH = (size_t)(m * 32 + quad * 8);   // halfs (E frags)
    size_t loB = (size_t)(m * 64 + quad * 16);  // bytes (V fp8 frags)

    // ---- G phase: K=512, 8 chunks of 64; fp8, no LDS, no barriers ----
    f32x4 gacc[4][4] = {};
    l2t aA[4], bA[4], aB[4], bB[4];

#define LOADC(c, a, b)                                                          \
    {                                                                           \
        _Pragma("unroll")                                                       \
        for (int im = 0; im < 4; ++im)                                          \
            a[im] = *(const l2t*)(VF8 + (((size_t)(rtA + im) * 8 + (c)) << 10) + loB); \
        _Pragma("unroll")                                                       \
        for (int jn = 0; jn < 4; ++jn)                                          \
            b[jn] = *(const l2t*)(VF8 + (((size_t)(rtB + jn) * 8 + (c)) << 10) + loB); \
    }
#define MMC(a, b)                                                               \
    {                                                                           \
        _Pragma("unroll")                                                       \
        for (int jn = 0; jn < 4; ++jn)                                          \
            _Pragma("unroll")                                                   \
            for (int im = 0; im < 4; ++im) {                                    \
                gacc[im][jn] = MFMA8(a[im][0], b[jn][0], gacc[im][jn]);         \
                gacc[im][jn] = MFMA8(a[im][1], b[jn][1], gacc[im][jn]);         \
            }                                                                   \
    }

    LOADC(0, aA, bA);
#pragma unroll
    for (int c = 0; c < 7; ++c) {
        if (c & 1) { LOADC(c + 1, aA, bA); MMC(aB, bB); }
        else       { LOADC(c + 1, aB, bB); MMC(aA, bA); }
    }
    MMC(aB, bB);                               // chunk 7 (loaded at c=6)

    // ---- fused S phase + epilogue (plain fp16, B-frags hoisted) ----
    half8 bh[4][2];
#pragma unroll
    for (int jn = 0; jn < 4; ++jn) {
        size_t bb = (size_t)(rtB + jn) * 2 * 512 + loH;
        bh[jn][0] = *(const half8*)(EFh + bb);
        bh[jn][1] = *(const half8*)(EFh + bb + 512);
    }
    float zj[4] = {}, nj_[4] = {};
#pragma unroll
    for (int im = 0; im < 4; ++im) {
        size_t ab = (size_t)(rtA + im) * 2 * 512 + loH;
        half8 ah0 = *(const half8*)(EFh + ab);
        half8 ah1 = *(const half8*)(EFh + ab + 512);
        f32x4 zi4 = {0.f, 0.f, 0.f, 0.f};
        f32x4 ni4 = {0.f, 0.f, 0.f, 0.f};
#pragma unroll
        for (int jn = 0; jn < 4; ++jn) {
            f32x4 acc = {0.f, 0.f, 0.f, 0.f};
            acc = MFMA16(ah0, bh[jn][0], acc);
            acc = MFMA16(ah1, bh[jn][1], acc);
            int jl = (wj << 6) + jn * 16 + m;
            int jg = j0 + jl;
            float nej = sNeJ[jl], nnj = sNJ[jl];
            f32x4 g4 = gacc[im][jn];
            bool p[4];
            bool anyp = false;
#pragma unroll
            for (int r = 0; r < 4; ++r) {
                int il = (wi << 6) + im * 16 + quad * 4 + r;
                int ig = i0 + il;
                float nei = sNeI[il];
                p[r] = (acc[r] > fminf(nei, nej) - SEL_T) && (!diag || ig < jg);
                anyp |= p[r];
            }
            if (__builtin_amdgcn_ballot_w64(anyp)) {   // wave-uniform skip
#pragma unroll
                for (int r = 0; r < 4; ++r) {
                    if (p[r]) {
                        int il = (wi << 6) + im * 16 + quad * 4 + r;
                        float nei = sNeI[il], nni = sNI[il];
                        float s = acc[r];
                        float wiw = __expf(s - nei);
                        float wjw = __expf(s - nej);
                        float wd = nni + nnj - 2.f * g4[r];
                        zi4[r] += wiw;  ni4[r] += wiw * wd;
                        zj[jn] += wjw;  nj_[jn] += wjw * wd;
                    }
                }
            }
        }
        // i-side: reduce over 16 m-lanes, write wj-plane
#pragma unroll
        for (int msk = 1; msk < 16; msk <<= 1) {
#pragma unroll
            for (int r = 0; r < 4; ++r) {
                zi4[r] += __shfl_xor(zi4[r], msk, 64);
                ni4[r] += __shfl_xor(ni4[r], msk, 64);
            }
        }
        if (m == 0) {
            int row0 = (wi << 6) + im * 16 + quad * 4;
            *(f32x4*)(scr + (wj << 7) + row0)       = zi4;
            *(f32x4*)(scr + 256 + (wj << 7) + row0) = ni4;
        }
    }
    // j-side: reduce over quads, write wi-plane
#pragma unroll
    for (int msk = 16; msk < 64; msk <<= 1) {
#pragma unroll
        for (int jn = 0; jn < 4; ++jn) {
            zj[jn]  += __shfl_xor(zj[jn],  msk, 64);
            nj_[jn] += __shfl_xor(nj_[jn], msk, 64);
        }
    }
    if (quad == 0) {
#pragma unroll
        for (int jn = 0; jn < 4; ++jn) {
            int jl = (wj << 6) + jn * 16 + m;
            scr[512 + (wi << 7) + jl] = zj[jn];
            scr[768 + (wi << 7) + jl] = nj_[jn];
        }
    }
    __syncthreads();
    // fold planes -> direct device atomics (zero-skip for empty rows)
    if (tid < 128) {
        float az = scr[tid]       + scr[128 + tid];
        float an = scr[256 + tid] + scr[384 + tid];
        if (az != 0.f || an != 0.f) {
            atomicAdd(Z + i0 + tid,   az);
            atomicAdd(num + i0 + tid, an);
        }
    } else {
        int cidx = tid - 128;
        float az = scr[512 + cidx] + scr[640 + cidx];
        float an = scr[768 + cidx] + scr[896 + cidx];
        if (az != 0.f || an != 0.f) {
            atomicAdd(Z + j0 + cidx,   az);
            atomicAdd(num + j0 + cidx, an);
        }
    }
#undef LOADC
#undef MMC
}

// -------- K2b: ABLATION — G phase only, x5 (measurement kernel) ---------
// Same decode, same (256,3), same frag addressing. REP=5 so dur ~ 5*G
// guarantees it tops the rocprof table (G floor ~17us -> 5G >= 85 > 70).
// Per-rep laundered loB defeats load CSE; asm sink keeps gacc live.
__global__ __launch_bounds__(256, 3) void k_mega_g(
    const unsigned char* __restrict__ VF8) {
    int bx, by;
    st_decode(blockIdx.x, bx, by);
    int i0 = bx << 7, j0 = by << 7;

    int tid = threadIdx.x;
    int wave = tid >> 6, lane = tid & 63;
    int m = lane & 15, quad = lane >> 4;
    int wi = wave & 1, wj = wave >> 1;
    int rtA = (i0 >> 4) + wi * 4;
    int rtB = (j0 >> 4) + wj * 4;
    size_t loB = (size_t)(m * 64 + quad * 16);

    f32x4 gacc[4][4] = {};

#define LOADC(c, a, b)                                                          \
    {                                                                           \
        _Pragma("unroll")                                                       \
        for (int im = 0; im < 4; ++im)                                          \
            a[im] = *(const l2t*)(VF8 + (((size_t)(rtA + im) * 8 + (c)) << 10) + loBr); \
        _Pragma("unroll")                                                       \
        for (int jn = 0; jn < 4; ++jn)                                          \
            b[jn] = *(const l2t*)(VF8 + (((size_t)(rtB + jn) * 8 + (c)) << 10) + loBr); \
    }
#define MMC(a, b)                                                               \
    {                                                                           \
        _Pragma("unroll")                                                       \
        for (int jn = 0; jn < 4; ++jn)                                          \
            _Pragma("unroll")                                                   \
            for (int im = 0; im < 4; ++im) {                                    \
                gacc[im][jn] = MFMA8(a[im][0], b[jn][0], gacc[im][jn]);         \
                gacc[im][jn] = MFMA8(a[im][1], b[jn][1], gacc[im][jn]);         \
            }                                                                   \
    }

#pragma unroll 1
    for (int rep = 0; rep < 5; ++rep) {
        size_t loBr = loB;
        asm volatile("" : "+v"(loBr));         // opaque per rep -> no load CSE
        l2t aA[4], bA[4], aB[4], bB[4];
        LOADC(0, aA, bA);
#pragma unroll
        for (int c = 0; c < 7; ++c) {
            if (c & 1) { LOADC(c + 1, aA, bA); MMC(aB, bB); }
            else       { LOADC(c + 1, aB, bB); MMC(aA, bA); }
        }
        MMC(aB, bB);
    }
#undef LOADC
#undef MMC

    // keep-alive sink (rule #17): gacc must stay live, no stores
#pragma unroll
    for (int im = 0; im < 4; ++im)
#pragma unroll
        for (int jn = 0; jn < 4; ++jn)
            asm volatile("" :: "v"(gacc[im][jn][0]), "v"(gacc[im][jn][1]),
                              "v"(gacc[im][jn][2]), "v"(gacc[im][jn][3]));
}

// ------- K3: trivial 8192-row reduce + last-block final fold ------------
__global__ __launch_bounds__(256) void k_red(
    const float* __restrict__ Z, const float* __restrict__ num,
    double* __restrict__ part, unsigned* __restrict__ cnt,
    float* __restrict__ out) {
    int r = (blockIdx.x << 8) + threadIdx.x;   // 32 blocks x 256 threads
    __shared__ double sd[256];
    sd[threadIdx.x] = (double)num[r] / (double)Z[r];
    __syncthreads();
    for (int st = 128; st > 0; st >>= 1) {
        if (threadIdx.x < st) sd[threadIdx.x] += sd[threadIdx.x + st];
        __syncthreads();
    }
    if (threadIdx.x == 0) {
        part[blockIdx.x] = sd[0];
        __threadfence();
        unsigned old = atomicAdd(cnt, 1u);
        if (old == 31u) {                // last block folds
            __threadfence();
            double a = 0.0;
            for (int k = 0; k < 32; ++k) a += part[k];
            out[0] = (float)(a / 67108864.0);   // / B^2
        }
    }
}

// ---------------- host launcher -----------------------------------------
extern "C" void kernel_launch(void* const* d_in, const int* in_sizes, int n_in,
                              void* d_out, int out_size, void* d_ws, size_t ws_size,
                              hipStream_t stream) {
    const float* V = (const float*)d_in[0];   // [8192, 512] f32
    const float* E = (const float*)d_in[1];   // [8192, 64]  f32
    float* out = (float*)d_out;
    char* ws = (char*)d_ws;

    float*         n_   = (float*)(ws + 0);            // 32 KB
    float*         ne   = (float*)(ws + 32768);        // 32 KB
    float*         Z    = (float*)(ws + 65536);        // 32 KB (init 1 in k_prep)
    float*         num  = (float*)(ws + 98304);        // 32 KB (init 0 in k_prep)
    unsigned char* VF8  = (unsigned char*)(ws + 131072);// 4 MB fp8 V frags
    _Float16*      EFh  = (_Float16*)(ws + 4325376);   // 1 MB
    double*        part = (double*)(ws + 5373952);     // 256 B
    unsigned*      cnt  = (unsigned*)(ws + 5374208);   // 4 B

    k_prep<<<512, 256, 0, stream>>>(V, E, n_, ne, Z, num, VF8, EFh, cnt);
    k_mega<<<2080, 256, 0, stream>>>(VF8, EFh, ne, n_, Z, num);
    k_mega_g<<<2080, 256, 0, stream>>>(VF8);           // ablation probe (5x G)
    k_red <<<32, 256, 0, stream>>>(Z, num, part, cnt, out);
}

// Round 6
// 229.272 us; speedup vs baseline: 1.8017x; 1.8017x over previous
//
#include <hip/hip_runtime.h>

// TangentSpaceLoss: loss = (1/B^2) sum_ij softmax_j(E E^T)_ij * ||v_i - v_j||^2
// B=8192, G=512, D=64.
//
// R19: R18's probe was spill-contaminated (asm "+v" laundering -> 108MB
// scratch WRITE, 339MB FETCH; 290us measures spill BW not G). Fixes:
//  (1) clean probe: per-rep base = VF8 + rep*dz, dz=0 kernel arg (no CSE,
//      no laundering, SGPR-only) -> rows = 5*G_gather, WRITE small iff clean.
//  (2) k_mega G-phase -> m97 structure: VF8 relayout to LANE-LINEAR frags
//      (k_prep stores frag (m,q) at byte (q*16+m)*16 so MFMA-lane l reads
//      l*16), async global_load_lds width=16 staging of each 16KB K-chunk
//      (16 ops, 4/wave), LDS double-buffer, ONE barrier/chunk (barrier at
//      iter c => all waves done reading buf[(c+1)&1] in iter c-1 -> restage
//      race-free), conflict-free linear ds_read_b128, unique data loaded
//      once (halves L2 requests).
// LDS: 32KB dbuf + 2KB norms + 4KB scr = 39KB, (256,3) holds (3x39=117<160).
//   S: fp16 MFMA (EFh frag-linear, B-frags hoisted), fused epilogue with
//      ballot-skip; LDS-plane cross-wave combine (R8-verified).
// Selection: s > min(ne_i,ne_j)-32 (safe superset). Softmax shift ne_i;
// diagonal w=1, wd=0 -> Z preinit 1.
//
// VF8 (NEW): [rt 512][c 8][lane 64][16B]; lane l = q*16+m holds A-row m,
// K-quad q (bytes 0-7 = kc0, 8-15 = kc1).
// EFh: [rt 512][kc 2][m 16][k' 32] halfs.

#define SEL_T 32.0f

typedef _Float16 half8 __attribute__((ext_vector_type(8)));
typedef float    f32x4 __attribute__((ext_vector_type(4)));
typedef long     l2t   __attribute__((ext_vector_type(2)));

#define MFMA16(a, b, c) __builtin_amdgcn_mfma_f32_16x16x32_f16(a, b, c, 0, 0, 0)
#define MFMA8(a, b, c)  __builtin_amdgcn_mfma_f32_16x16x32_fp8_fp8(a, b, c, 0, 0, 0)

// Shared super-tile decode: blk0 -> (bx<=by), XCD-windowed.
__device__ __forceinline__ void st_decode(int blk0, int& bx, int& by) {
    int g = (blk0 & 7) * 260 + (blk0 >> 3);
    int SY = 0;
#pragma unroll
    for (int s = 1; s < 8; ++s) if (32 * s * s + 4 * s <= g) SY = s;
    int rr = g - (32 * SY * SY + 4 * SY);
    if (rr < 64 * SY) {                         // off-diagonal ST (full 8x8)
        int SX = rr >> 6, t = rr & 63;
        bx = (SX << 3) + (t & 7);
        by = (SY << 3) + (t >> 3);
    } else {                                    // diagonal ST (36 blocks)
        int t = rr - 64 * SY;
        int ly = 0;
#pragma unroll
        for (int s = 1; s < 8; ++s) if (s * (s + 1) / 2 <= t) ly = s;
        int lx = t - ly * (ly + 1) / 2;
        bx = (SY << 3) + lx;
        by = (SY << 3) + ly;
    }
}

// ---------------- K1: norms + fp8 V + fp16 E layouts + Z/num init -------
__global__ __launch_bounds__(256) void k_prep(
    const float* __restrict__ V, const float* __restrict__ E,
    float* __restrict__ n, float* __restrict__ ne,
    float* __restrict__ Z, float* __restrict__ num,
    unsigned char* __restrict__ VF8, _Float16* __restrict__ EFh,
    unsigned* __restrict__ cnt) {
    int rt = blockIdx.x;                       // 512 row-tiles of 16 rows
    int tid = threadIdx.x, wave = tid >> 6, lane = tid & 63;
    if (rt == 0 && tid == 0) *cnt = 0;
    int m = lane >> 2, q = lane & 3;
    int row = rt * 16 + m;
    const float* vr = V + (size_t)row * 512;
    float sn = 0.f;
#pragma unroll
    for (int it = 0; it < 2; ++it) {
        int c = wave + it * 4;                 // K-chunk of 64
        const float4* p0 = (const float4*)(vr + c * 64 + q * 8);
        const float4* p1 = (const float4*)(vr + c * 64 + 32 + q * 8);
        float4 a0 = p0[0], a1 = p0[1], b0 = p1[0], b1 = p1[1];
        int w0 = 0, w1 = 0, w2 = 0, w3 = 0;
        w0 = __builtin_amdgcn_cvt_pk_fp8_f32(a0.x, a0.y, w0, false);
        w0 = __builtin_amdgcn_cvt_pk_fp8_f32(a0.z, a0.w, w0, true);
        w1 = __builtin_amdgcn_cvt_pk_fp8_f32(a1.x, a1.y, w1, false);
        w1 = __builtin_amdgcn_cvt_pk_fp8_f32(a1.z, a1.w, w1, true);
        w2 = __builtin_amdgcn_cvt_pk_fp8_f32(b0.x, b0.y, w2, false);
        w2 = __builtin_amdgcn_cvt_pk_fp8_f32(b0.z, b0.w, w2, true);
        w3 = __builtin_amdgcn_cvt_pk_fp8_f32(b1.x, b1.y, w3, false);
        w3 = __builtin_amdgcn_cvt_pk_fp8_f32(b1.z, b1.w, w3, true);
        uint4 o;
        o.x = (unsigned)w0; o.y = (unsigned)w1;
        o.z = (unsigned)w2; o.w = (unsigned)w3;
        // LANE-LINEAR relayout: frag for (m,q) -> reader-lane l = q*16+m,
        // byte offset l*16 = (q<<8) + (m<<4).
        *(uint4*)(VF8 + (((size_t)rt * 8 + c) << 10) + ((size_t)q << 8) + ((size_t)m << 4)) = o;
        sn += a0.x*a0.x + a0.y*a0.y + a0.z*a0.z + a0.w*a0.w
            + a1.x*a1.x + a1.y*a1.y + a1.z*a1.z + a1.w*a1.w
            + b0.x*b0.x + b0.y*b0.y + b0.z*b0.z + b0.w*b0.w
            + b1.x*b1.x + b1.y*b1.y + b1.z*b1.z + b1.w*b1.w;
    }
    __shared__ float sred[4][64];
    sred[wave][lane] = sn;
    __syncthreads();
    if (tid < 16) {
        float s = 0.f;
#pragma unroll
        for (int w = 0; w < 4; ++w)
#pragma unroll
            for (int qq = 0; qq < 4; ++qq) s += sred[w][tid * 4 + qq];
        int rr = rt * 16 + tid;
        n[rr] = s;
        Z[rr] = 1.0f;                          // diagonal w=1, wd=0
        num[rr] = 0.0f;
    }
    // E: threads 0..127: rl = t>>3, u = t&7, k in [u*8, u*8+8)
    if (tid < 128) {
        int rl = tid >> 3, u = tid & 7;
        int erow = rt * 16 + rl;
        const float4* er = (const float4*)(E + (size_t)erow * 64);
        float4 x0 = er[u * 2], x1 = er[u * 2 + 1];
        float xf[8] = {x0.x, x0.y, x0.z, x0.w, x1.x, x1.y, x1.z, x1.w};
        half8 h;
        float se = 0.f;
#pragma unroll
        for (int k = 0; k < 8; ++k) {
            h[k] = (_Float16)xf[k];
            se += xf[k] * xf[k];
        }
        int kc = u >> 2, qq = u & 3;
        *(half8*)(EFh + ((size_t)rt * 2 + kc) * 512 + rl * 32 + qq * 8) = h;
        se += __shfl_xor(se, 1, 64);
        se += __shfl_xor(se, 2, 64);
        se += __shfl_xor(se, 4, 64);
        if (u == 0) ne[erow] = se;
    }
}

// ---------------- K2: LDS-staged tile kernel (m97 structure) ------------
// 256 thr = 4 waves in 2x2 grid; wave tile 64x64 = 4x4 MFMA tiles.
// Per K-chunk: 16 async global_load_lds (4/wave) stage 16KB; dbuf; 1 barrier.
__global__ __launch_bounds__(256, 3) void k_mega(
    const unsigned char* __restrict__ VF8, const _Float16* __restrict__ EFh,
    const float* __restrict__ ne, const float* __restrict__ nrm,
    float* __restrict__ Z, float* __restrict__ num) {
    int bx, by;
    st_decode(blockIdx.x, bx, by);
    int i0 = bx << 7, j0 = by << 7;
    bool diag = (bx == by);

    __shared__ unsigned char ldsV[2][16384];   // [buf][slot 16][1KB]; 0-7 A, 8-15 B
    __shared__ float sNeI[128], sNeJ[128], sNI[128], sNJ[128];
    __shared__ float scr[1024];

    int tid = threadIdx.x;
    if (tid < 128) { sNeI[tid] = ne[i0 + tid]; sNI[tid] = nrm[i0 + tid]; }
    else { sNeJ[tid - 128] = ne[j0 + tid - 128]; sNJ[tid - 128] = nrm[j0 + tid - 128]; }

    int wave = tid >> 6, lane = tid & 63;
    int m = lane & 15, quad = lane >> 4;
    int wi = wave & 1, wj = wave >> 1;
    int rtA0 = i0 >> 4, rtB0 = j0 >> 4;
    size_t loH = (size_t)(m * 32 + quad * 8);   // halfs (E frags)
    size_t lo16 = (size_t)lane << 4;            // lane-linear 16B frag offset

    __syncthreads();   // norms staged (also pre-loop barrier)

    // stage slot s (0-7: A rt rtA0+s; 8-15: B rt rtB0+s-8), chunk c -> buf
#define STAGE(buf, c)                                                           \
    {                                                                           \
        _Pragma("unroll")                                                       \
        for (int k = 0; k < 4; ++k) {                                           \
            int s = (wave << 2) + k;                                            \
            int rt = (s < 8) ? (rtA0 + s) : (rtB0 + s - 8);                     \
            __builtin_amdgcn_global_load_lds(                                   \
                (const unsigned int*)(VF8 + (((size_t)rt * 8 + (c)) << 10) + lo16), \
                (unsigned int*)(&ldsV[buf][(size_t)s << 10]), 16, 0, 0);        \
        }                                                                       \
    }

    // ---- G phase: K=512, 8 chunks; async-staged LDS, dbuf, 1 barrier/chunk
    f32x4 gacc[4][4] = {};
    STAGE(0, 0);
#pragma unroll
    for (int c = 0; c < 8; ++c) {
        __syncthreads();                       // buf[c&1] staged (vmcnt0+bar)
        if (c < 7) STAGE((c + 1) & 1, c + 1);  // async into other buf (race-free)
        l2t a[4], b[4];
#pragma unroll
        for (int im = 0; im < 4; ++im)
            a[im] = *(const l2t*)(&ldsV[c & 1][(size_t)((wi << 2) + im) << 10] + lo16);
#pragma unroll
        for (int jn = 0; jn < 4; ++jn)
            b[jn] = *(const l2t*)(&ldsV[c & 1][(size_t)(8 + (wj << 2) + jn) << 10] + lo16);
#pragma unroll
        for (int jn = 0; jn < 4; ++jn)
#pragma unroll
            for (int im = 0; im < 4; ++im) {
                gacc[im][jn] = MFMA8(a[im][0], b[jn][0], gacc[im][jn]);
                gacc[im][jn] = MFMA8(a[im][1], b[jn][1], gacc[im][jn]);
            }
    }
#undef STAGE

    // ---- fused S phase + epilogue (plain fp16, B-frags hoisted) ----
    int rtA = rtA0 + wi * 4;
    int rtB = rtB0 + wj * 4;
    half8 bh[4][2];
#pragma unroll
    for (int jn = 0; jn < 4; ++jn) {
        size_t bb = (size_t)(rtB + jn) * 2 * 512 + loH;
        bh[jn][0] = *(const half8*)(EFh + bb);
        bh[jn][1] = *(const half8*)(EFh + bb + 512);
    }
    float zj[4] = {}, nj_[4] = {};
#pragma unroll
    for (int im = 0; im < 4; ++im) {
        size_t ab = (size_t)(rtA + im) * 2 * 512 + loH;
        half8 ah0 = *(const half8*)(EFh + ab);
        half8 ah1 = *(const half8*)(EFh + ab + 512);
        f32x4 zi4 = {0.f, 0.f, 0.f, 0.f};
        f32x4 ni4 = {0.f, 0.f, 0.f, 0.f};
#pragma unroll
        for (int jn = 0; jn < 4; ++jn) {
            f32x4 acc = {0.f, 0.f, 0.f, 0.f};
            acc = MFMA16(ah0, bh[jn][0], acc);
            acc = MFMA16(ah1, bh[jn][1], acc);
            int jl = (wj << 6) + jn * 16 + m;
            int jg = j0 + jl;
            float nej = sNeJ[jl], nnj = sNJ[jl];
            f32x4 g4 = gacc[im][jn];
            bool p[4];
            bool anyp = false;
#pragma unroll
            for (int r = 0; r < 4; ++r) {
                int il = (wi << 6) + im * 16 + quad * 4 + r;
                int ig = i0 + il;
                float nei = sNeI[il];
                p[r] = (acc[r] > fminf(nei, nej) - SEL_T) && (!diag || ig < jg);
                anyp |= p[r];
            }
            if (__builtin_amdgcn_ballot_w64(anyp)) {   // wave-uniform skip
#pragma unroll
                for (int r = 0; r < 4; ++r) {
                    if (p[r]) {
                        int il = (wi << 6) + im * 16 + quad * 4 + r;
                        float nei = sNeI[il], nni = sNI[il];
                        float s = acc[r];
                        float wiw = __expf(s - nei);
                        float wjw = __expf(s - nej);
                        float wd = nni + nnj - 2.f * g4[r];
                        zi4[r] += wiw;  ni4[r] += wiw * wd;
                        zj[jn] += wjw;  nj_[jn] += wjw * wd;
                    }
                }
            }
        }
        // i-side: reduce over 16 m-lanes, write wj-plane
#pragma unroll
        for (int msk = 1; msk < 16; msk <<= 1) {
#pragma unroll
            for (int r = 0; r < 4; ++r) {
                zi4[r] += __shfl_xor(zi4[r], msk, 64);
                ni4[r] += __shfl_xor(ni4[r], msk, 64);
            }
        }
        if (m == 0) {
            int row0 = (wi << 6) + im * 16 + quad * 4;
            *(f32x4*)(scr + (wj << 7) + row0)       = zi4;
            *(f32x4*)(scr + 256 + (wj << 7) + row0) = ni4;
        }
    }
    // j-side: reduce over quads, write wi-plane
#pragma unroll
    for (int msk = 16; msk < 64; msk <<= 1) {
#pragma unroll
        for (int jn = 0; jn < 4; ++jn) {
            zj[jn]  += __shfl_xor(zj[jn],  msk, 64);
            nj_[jn] += __shfl_xor(nj_[jn], msk, 64);
        }
    }
    if (quad == 0) {
#pragma unroll
        for (int jn = 0; jn < 4; ++jn) {
            int jl = (wj << 6) + jn * 16 + m;
            scr[512 + (wi << 7) + jl] = zj[jn];
            scr[768 + (wi << 7) + jl] = nj_[jn];
        }
    }
    __syncthreads();
    // fold planes -> direct device atomics (zero-skip for empty rows)
    if (tid < 128) {
        float az = scr[tid]       + scr[128 + tid];
        float an = scr[256 + tid] + scr[384 + tid];
        if (az != 0.f || an != 0.f) {
            atomicAdd(Z + i0 + tid,   az);
            atomicAdd(num + i0 + tid, an);
        }
    } else {
        int cidx = tid - 128;
        float az = scr[512 + cidx] + scr[640 + cidx];
        float an = scr[768 + cidx] + scr[896 + cidx];
        if (az != 0.f || an != 0.f) {
            atomicAdd(Z + j0 + cidx,   az);
            atomicAdd(num + j0 + cidx, an);
        }
    }
}

// -------- K2b: ABLATION probe — gather-G only, x5 (spill-proof) ---------
// Measures the OLD zero-LDS gather G-phase on the new lane-linear layout.
// dz = 0 at runtime (host-passed): per-rep base VF8 + rep*dz is formally
// distinct (defeats CSE) at SGPR-only cost -> no laundering, no spill.
// Rows = 5 * G_gather. Clean iff WRITE_SIZE small.
__global__ __launch_bounds__(256, 3) void k_mega_g(
    const unsigned char* __restrict__ VF8, unsigned long long dz) {
    int bx, by;
    st_decode(blockIdx.x, bx, by);
    int i0 = bx << 7, j0 = by << 7;

    int tid = threadIdx.x;
    int wave = tid >> 6, lane = tid & 63;
    int wi = wave & 1, wj = wave >> 1;
    int rtA = (i0 >> 4) + wi * 4;
    int rtB = (j0 >> 4) + wj * 4;
    size_t lo16 = (size_t)lane << 4;

    f32x4 gacc[4][4] = {};

#define LOADC(c, a, b)                                                          \
    {                                                                           \
        _Pragma("unroll")                                                       \
        for (int im = 0; im < 4; ++im)                                          \
            a[im] = *(const l2t*)(vb + (((size_t)(rtA + im) * 8 + (c)) << 10) + lo16); \
        _Pragma("unroll")                                                       \
        for (int jn = 0; jn < 4; ++jn)                                          \
            b[jn] = *(const l2t*)(vb + (((size_t)(rtB + jn) * 8 + (c)) << 10) + lo16); \
    }
#define MMC(a, b)                                                               \
    {                                                                           \
        _Pragma("unroll")                                                       \
        for (int jn = 0; jn < 4; ++jn)                                          \
            _Pragma("unroll")                                                   \
            for (int im = 0; im < 4; ++im) {                                    \
                gacc[im][jn] = MFMA8(a[im][0], b[jn][0], gacc[im][jn]);         \
                gacc[im][jn] = MFMA8(a[im][1], b[jn][1], gacc[im][jn]);         \
            }                                                                   \
    }

#pragma unroll 1
    for (int rep = 0; rep < 5; ++rep) {
        const unsigned char* vb = VF8 + (size_t)rep * dz;  // runtime-0 shift
        l2t aA[4], bA[4], aB[4], bB[4];
        LOADC(0, aA, bA);
#pragma unroll
        for (int c = 0; c < 7; ++c) {
            if (c & 1) { LOADC(c + 1, aA, bA); MMC(aB, bB); }
            else       { LOADC(c + 1, aB, bB); MMC(aA, bA); }
        }
        MMC(aB, bB);
    }
#undef LOADC
#undef MMC

    // keep-alive sink (rule #17)
#pragma unroll
    for (int im = 0; im < 4; ++im)
#pragma unroll
        for (int jn = 0; jn < 4; ++jn)
            asm volatile("" :: "v"(gacc[im][jn][0]), "v"(gacc[im][jn][1]),
                              "v"(gacc[im][jn][2]), "v"(gacc[im][jn][3]));
}

// ------- K3: trivial 8192-row reduce + last-block final fold ------------
__global__ __launch_bounds__(256) void k_red(
    const float* __restrict__ Z, const float* __restrict__ num,
    double* __restrict__ part, unsigned* __restrict__ cnt,
    float* __restrict__ out) {
    int r = (blockIdx.x << 8) + threadIdx.x;   // 32 blocks x 256 threads
    __shared__ double sd[256];
    sd[threadIdx.x] = (double)num[r] / (double)Z[r];
    __syncthreads();
    for (int st = 128; st > 0; st >>= 1) {
        if (threadIdx.x < st) sd[threadIdx.x] += sd[threadIdx.x + st];
        __syncthreads();
    }
    if (threadIdx.x == 0) {
        part[blockIdx.x] = sd[0];
        __threadfence();
        unsigned old = atomicAdd(cnt, 1u);
        if (old == 31u) {                // last block folds
            __threadfence();
            double a = 0.0;
            for (int k = 0; k < 32; ++k) a += part[k];
            out[0] = (float)(a / 67108864.0);   // / B^2
        }
    }
}

// ---------------- host launcher -----------------------------------------
extern "C" void kernel_launch(void* const* d_in, const int* in_sizes, int n_in,
                              void* d_out, int out_size, void* d_ws, size_t ws_size,
                              hipStream_t stream) {
    const float* V = (const float*)d_in[0];   // [8192, 512] f32
    const float* E = (const float*)d_in[1];   // [8192, 64]  f32
    float* out = (float*)d_out;
    char* ws = (char*)d_ws;

    float*         n_   = (float*)(ws + 0);            // 32 KB
    float*         ne   = (float*)(ws + 32768);        // 32 KB
    float*         Z    = (float*)(ws + 65536);        // 32 KB (init 1 in k_prep)
    float*         num  = (float*)(ws + 98304);        // 32 KB (init 0 in k_prep)
    unsigned char* VF8  = (unsigned char*)(ws + 131072);// 4 MB fp8 V frags
    _Float16*      EFh  = (_Float16*)(ws + 4325376);   // 1 MB
    double*        part = (double*)(ws + 5373952);     // 256 B
    unsigned*      cnt  = (unsigned*)(ws + 5374208);   // 4 B

    k_prep<<<512, 256, 0, stream>>>(V, E, n_, ne, Z, num, VF8, EFh, cnt);
    k_mega<<<2080, 256, 0, stream>>>(VF8, EFh, ne, n_, Z, num);
    k_mega_g<<<2080, 256, 0, stream>>>(VF8, 0ull);     // clean probe (5x gather-G)
    k_red <<<32, 256, 0, stream>>>(Z, num, part, cnt, out);
}

// Round 7
// 122.467 us; speedup vs baseline: 3.3729x; 1.8721x over previous
//
#include <hip/hip_runtime.h>

// TangentSpaceLoss: loss = (1/B^2) sum_ij softmax_j(E E^T)_ij * ||v_i - v_j||^2
// B=8192, G=512, D=64.
//
// R20: R19 probe (clean, WRITE=0) measured gather-G = 23.6us (MfmaUtil 65%)
// -> G was never the 70us bottleneck. Meanwhile the LDS-staged k_mega came
// in at ~46us (229 total - 118 probe - 65 fixed), a 24us win over the 70us
// gather version: staging de-dupes the 2x redundant A/B fragment gathers and
// hides load latency under MFMA via async global_load_lds + dbuf.
// R20 = harvest: REMOVE the probe, keep k_mega/k_prep/k_red byte-identical.
// Expect k_mega ~46us in counters (top dispatch), total ~108-115us.
// Next-round decision from fresh counters: S-epilogue VALU vs deeper G
// pipeline vs fixed-cost (launch gap / k_prep) trimming.
//
//   G: LDS-staged fp8 MFMA K=512 (m97 structure): lane-linear VF8 frags,
//      16x global_load_lds(width=16)/chunk (4/wave), LDS dbuf, 1 barrier
//      per chunk, conflict-free linear ds_read_b128.
//   S: fp16 MFMA (EFh frag-linear, B-frags hoisted), fused epilogue with
//      ballot-skip; LDS-plane cross-wave combine (R8-verified).
// Selection: s > min(ne_i,ne_j)-32 (safe superset). Softmax shift ne_i;
// diagonal w=1, wd=0 -> Z preinit 1.
// LDS: 32KB dbuf + 2KB norms + 4KB scr = 39KB, (256,3) holds.
//
// VF8: [rt 512][c 8][lane 64][16B]; lane l = q*16+m holds A-row m,
// K-quad q (bytes 0-7 = kc0, 8-15 = kc1).
// EFh: [rt 512][kc 2][m 16][k' 32] halfs.

#define SEL_T 32.0f

typedef _Float16 half8 __attribute__((ext_vector_type(8)));
typedef float    f32x4 __attribute__((ext_vector_type(4)));
typedef long     l2t   __attribute__((ext_vector_type(2)));

#define MFMA16(a, b, c) __builtin_amdgcn_mfma_f32_16x16x32_f16(a, b, c, 0, 0, 0)
#define MFMA8(a, b, c)  __builtin_amdgcn_mfma_f32_16x16x32_fp8_fp8(a, b, c, 0, 0, 0)

// Shared super-tile decode: blk0 -> (bx<=by), XCD-windowed.
__device__ __forceinline__ void st_decode(int blk0, int& bx, int& by) {
    int g = (blk0 & 7) * 260 + (blk0 >> 3);
    int SY = 0;
#pragma unroll
    for (int s = 1; s < 8; ++s) if (32 * s * s + 4 * s <= g) SY = s;
    int rr = g - (32 * SY * SY + 4 * SY);
    if (rr < 64 * SY) {                         // off-diagonal ST (full 8x8)
        int SX = rr >> 6, t = rr & 63;
        bx = (SX << 3) + (t & 7);
        by = (SY << 3) + (t >> 3);
    } else {                                    // diagonal ST (36 blocks)
        int t = rr - 64 * SY;
        int ly = 0;
#pragma unroll
        for (int s = 1; s < 8; ++s) if (s * (s + 1) / 2 <= t) ly = s;
        int lx = t - ly * (ly + 1) / 2;
        bx = (SY << 3) + lx;
        by = (SY << 3) + ly;
    }
}

// ---------------- K1: norms + fp8 V + fp16 E layouts + Z/num init -------
__global__ __launch_bounds__(256) void k_prep(
    const float* __restrict__ V, const float* __restrict__ E,
    float* __restrict__ n, float* __restrict__ ne,
    float* __restrict__ Z, float* __restrict__ num,
    unsigned char* __restrict__ VF8, _Float16* __restrict__ EFh,
    unsigned* __restrict__ cnt) {
    int rt = blockIdx.x;                       // 512 row-tiles of 16 rows
    int tid = threadIdx.x, wave = tid >> 6, lane = tid & 63;
    if (rt == 0 && tid == 0) *cnt = 0;
    int m = lane >> 2, q = lane & 3;
    int row = rt * 16 + m;
    const float* vr = V + (size_t)row * 512;
    float sn = 0.f;
#pragma unroll
    for (int it = 0; it < 2; ++it) {
        int c = wave + it * 4;                 // K-chunk of 64
        const float4* p0 = (const float4*)(vr + c * 64 + q * 8);
        const float4* p1 = (const float4*)(vr + c * 64 + 32 + q * 8);
        float4 a0 = p0[0], a1 = p0[1], b0 = p1[0], b1 = p1[1];
        int w0 = 0, w1 = 0, w2 = 0, w3 = 0;
        w0 = __builtin_amdgcn_cvt_pk_fp8_f32(a0.x, a0.y, w0, false);
        w0 = __builtin_amdgcn_cvt_pk_fp8_f32(a0.z, a0.w, w0, true);
        w1 = __builtin_amdgcn_cvt_pk_fp8_f32(a1.x, a1.y, w1, false);
        w1 = __builtin_amdgcn_cvt_pk_fp8_f32(a1.z, a1.w, w1, true);
        w2 = __builtin_amdgcn_cvt_pk_fp8_f32(b0.x, b0.y, w2, false);
        w2 = __builtin_amdgcn_cvt_pk_fp8_f32(b0.z, b0.w, w2, true);
        w3 = __builtin_amdgcn_cvt_pk_fp8_f32(b1.x, b1.y, w3, false);
        w3 = __builtin_amdgcn_cvt_pk_fp8_f32(b1.z, b1.w, w3, true);
        uint4 o;
        o.x = (unsigned)w0; o.y = (unsigned)w1;
        o.z = (unsigned)w2; o.w = (unsigned)w3;
        // LANE-LINEAR layout: frag for (m,q) -> reader-lane l = q*16+m,
        // byte offset l*16 = (q<<8) + (m<<4).
        *(uint4*)(VF8 + (((size_t)rt * 8 + c) << 10) + ((size_t)q << 8) + ((size_t)m << 4)) = o;
        sn += a0.x*a0.x + a0.y*a0.y + a0.z*a0.z + a0.w*a0.w
            + a1.x*a1.x + a1.y*a1.y + a1.z*a1.z + a1.w*a1.w
            + b0.x*b0.x + b0.y*b0.y + b0.z*b0.z + b0.w*b0.w
            + b1.x*b1.x + b1.y*b1.y + b1.z*b1.z + b1.w*b1.w;
    }
    __shared__ float sred[4][64];
    sred[wave][lane] = sn;
    __syncthreads();
    if (tid < 16) {
        float s = 0.f;
#pragma unroll
        for (int w = 0; w < 4; ++w)
#pragma unroll
            for (int qq = 0; qq < 4; ++qq) s += sred[w][tid * 4 + qq];
        int rr = rt * 16 + tid;
        n[rr] = s;
        Z[rr] = 1.0f;                          // diagonal w=1, wd=0
        num[rr] = 0.0f;
    }
    // E: threads 0..127: rl = t>>3, u = t&7, k in [u*8, u*8+8)
    if (tid < 128) {
        int rl = tid >> 3, u = tid & 7;
        int erow = rt * 16 + rl;
        const float4* er = (const float4*)(E + (size_t)erow * 64);
        float4 x0 = er[u * 2], x1 = er[u * 2 + 1];
        float xf[8] = {x0.x, x0.y, x0.z, x0.w, x1.x, x1.y, x1.z, x1.w};
        half8 h;
        float se = 0.f;
#pragma unroll
        for (int k = 0; k < 8; ++k) {
            h[k] = (_Float16)xf[k];
            se += xf[k] * xf[k];
        }
        int kc = u >> 2, qq = u & 3;
        *(half8*)(EFh + ((size_t)rt * 2 + kc) * 512 + rl * 32 + qq * 8) = h;
        se += __shfl_xor(se, 1, 64);
        se += __shfl_xor(se, 2, 64);
        se += __shfl_xor(se, 4, 64);
        if (u == 0) ne[erow] = se;
    }
}

// ---------------- K2: LDS-staged tile kernel (m97 structure) ------------
// 256 thr = 4 waves in 2x2 grid; wave tile 64x64 = 4x4 MFMA tiles.
// Per K-chunk: 16 async global_load_lds (4/wave) stage 16KB; dbuf; 1 barrier.
__global__ __launch_bounds__(256, 3) void k_mega(
    const unsigned char* __restrict__ VF8, const _Float16* __restrict__ EFh,
    const float* __restrict__ ne, const float* __restrict__ nrm,
    float* __restrict__ Z, float* __restrict__ num) {
    int bx, by;
    st_decode(blockIdx.x, bx, by);
    int i0 = bx << 7, j0 = by << 7;
    bool diag = (bx == by);

    __shared__ unsigned char ldsV[2][16384];   // [buf][slot 16][1KB]; 0-7 A, 8-15 B
    __shared__ float sNeI[128], sNeJ[128], sNI[128], sNJ[128];
    __shared__ float scr[1024];

    int tid = threadIdx.x;
    if (tid < 128) { sNeI[tid] = ne[i0 + tid]; sNI[tid] = nrm[i0 + tid]; }
    else { sNeJ[tid - 128] = ne[j0 + tid - 128]; sNJ[tid - 128] = nrm[j0 + tid - 128]; }

    int wave = tid >> 6, lane = tid & 63;
    int m = lane & 15, quad = lane >> 4;
    int wi = wave & 1, wj = wave >> 1;
    int rtA0 = i0 >> 4, rtB0 = j0 >> 4;
    size_t loH = (size_t)(m * 32 + quad * 8);   // halfs (E frags)
    size_t lo16 = (size_t)lane << 4;            // lane-linear 16B frag offset

    __syncthreads();   // norms staged (also pre-loop barrier)

    // stage slot s (0-7: A rt rtA0+s; 8-15: B rt rtB0+s-8), chunk c -> buf
#define STAGE(buf, c)                                                           \
    {                                                                           \
        _Pragma("unroll")                                                       \
        for (int k = 0; k < 4; ++k) {                                           \
            int s = (wave << 2) + k;                                            \
            int rt = (s < 8) ? (rtA0 + s) : (rtB0 + s - 8);                     \
            __builtin_amdgcn_global_load_lds(                                   \
                (const unsigned int*)(VF8 + (((size_t)rt * 8 + (c)) << 10) + lo16), \
                (unsigned int*)(&ldsV[buf][(size_t)s << 10]), 16, 0, 0);        \
        }                                                                       \
    }

    // ---- G phase: K=512, 8 chunks; async-staged LDS, dbuf, 1 barrier/chunk
    f32x4 gacc[4][4] = {};
    STAGE(0, 0);
#pragma unroll
    for (int c = 0; c < 8; ++c) {
        __syncthreads();                       // buf[c&1] staged (vmcnt0+bar)
        if (c < 7) STAGE((c + 1) & 1, c + 1);  // async into other buf (race-free)
        l2t a[4], b[4];
#pragma unroll
        for (int im = 0; im < 4; ++im)
            a[im] = *(const l2t*)(&ldsV[c & 1][(size_t)((wi << 2) + im) << 10] + lo16);
#pragma unroll
        for (int jn = 0; jn < 4; ++jn)
            b[jn] = *(const l2t*)(&ldsV[c & 1][(size_t)(8 + (wj << 2) + jn) << 10] + lo16);
#pragma unroll
        for (int jn = 0; jn < 4; ++jn)
#pragma unroll
            for (int im = 0; im < 4; ++im) {
                gacc[im][jn] = MFMA8(a[im][0], b[jn][0], gacc[im][jn]);
                gacc[im][jn] = MFMA8(a[im][1], b[jn][1], gacc[im][jn]);
            }
    }
#undef STAGE

    // ---- fused S phase + epilogue (plain fp16, B-frags hoisted) ----
    int rtA = rtA0 + wi * 4;
    int rtB = rtB0 + wj * 4;
    half8 bh[4][2];
#pragma unroll
    for (int jn = 0; jn < 4; ++jn) {
        size_t bb = (size_t)(rtB + jn) * 2 * 512 + loH;
        bh[jn][0] = *(const half8*)(EFh + bb);
        bh[jn][1] = *(const half8*)(EFh + bb + 512);
    }
    float zj[4] = {}, nj_[4] = {};
#pragma unroll
    for (int im = 0; im < 4; ++im) {
        size_t ab = (size_t)(rtA + im) * 2 * 512 + loH;
        half8 ah0 = *(const half8*)(EFh + ab);
        half8 ah1 = *(const half8*)(EFh + ab + 512);
        f32x4 zi4 = {0.f, 0.f, 0.f, 0.f};
        f32x4 ni4 = {0.f, 0.f, 0.f, 0.f};
#pragma unroll
        for (int jn = 0; jn < 4; ++jn) {
            f32x4 acc = {0.f, 0.f, 0.f, 0.f};
            acc = MFMA16(ah0, bh[jn][0], acc);
            acc = MFMA16(ah1, bh[jn][1], acc);
            int jl = (wj << 6) + jn * 16 + m;
            int jg = j0 + jl;
            float nej = sNeJ[jl], nnj = sNJ[jl];
            f32x4 g4 = gacc[im][jn];
            bool p[4];
            bool anyp = false;
#pragma unroll
            for (int r = 0; r < 4; ++r) {
                int il = (wi << 6) + im * 16 + quad * 4 + r;
                int ig = i0 + il;
                float nei = sNeI[il];
                p[r] = (acc[r] > fminf(nei, nej) - SEL_T) && (!diag || ig < jg);
                anyp |= p[r];
            }
            if (__builtin_amdgcn_ballot_w64(anyp)) {   // wave-uniform skip
#pragma unroll
                for (int r = 0; r < 4; ++r) {
                    if (p[r]) {
                        int il = (wi << 6) + im * 16 + quad * 4 + r;
                        float nei = sNeI[il], nni = sNI[il];
                        float s = acc[r];
                        float wiw = __expf(s - nei);
                        float wjw = __expf(s - nej);
                        float wd = nni + nnj - 2.f * g4[r];
                        zi4[r] += wiw;  ni4[r] += wiw * wd;
                        zj[jn] += wjw;  nj_[jn] += wjw * wd;
                    }
                }
            }
        }
        // i-side: reduce over 16 m-lanes, write wj-plane
#pragma unroll
        for (int msk = 1; msk < 16; msk <<= 1) {
#pragma unroll
            for (int r = 0; r < 4; ++r) {
                zi4[r] += __shfl_xor(zi4[r], msk, 64);
                ni4[r] += __shfl_xor(ni4[r], msk, 64);
            }
        }
        if (m == 0) {
            int row0 = (wi << 6) + im * 16 + quad * 4;
            *(f32x4*)(scr + (wj << 7) + row0)       = zi4;
            *(f32x4*)(scr + 256 + (wj << 7) + row0) = ni4;
        }
    }
    // j-side: reduce over quads, write wi-plane
#pragma unroll
    for (int msk = 16; msk < 64; msk <<= 1) {
#pragma unroll
        for (int jn = 0; jn < 4; ++jn) {
            zj[jn]  += __shfl_xor(zj[jn],  msk, 64);
            nj_[jn] += __shfl_xor(nj_[jn], msk, 64);
        }
    }
    if (quad == 0) {
#pragma unroll
        for (int jn = 0; jn < 4; ++jn) {
            int jl = (wj << 6) + jn * 16 + m;
            scr[512 + (wi << 7) + jl] = zj[jn];
            scr[768 + (wi << 7) + jl] = nj_[jn];
        }
    }
    __syncthreads();
    // fold planes -> direct device atomics (zero-skip for empty rows)
    if (tid < 128) {
        float az = scr[tid]       + scr[128 + tid];
        float an = scr[256 + tid] + scr[384 + tid];
        if (az != 0.f || an != 0.f) {
            atomicAdd(Z + i0 + tid,   az);
            atomicAdd(num + i0 + tid, an);
        }
    } else {
        int cidx = tid - 128;
        float az = scr[512 + cidx] + scr[640 + cidx];
        float an = scr[768 + cidx] + scr[896 + cidx];
        if (az != 0.f || an != 0.f) {
            atomicAdd(Z + j0 + cidx,   az);
            atomicAdd(num + j0 + cidx, an);
        }
    }
}

// ------- K3: trivial 8192-row reduce + last-block final fold ------------
__global__ __launch_bounds__(256) void k_red(
    const float* __restrict__ Z, const float* __restrict__ num,
    double* __restrict__ part, unsigned* __restrict__ cnt,
    float* __restrict__ out) {
    int r = (blockIdx.x << 8) + threadIdx.x;   // 32 blocks x 256 threads
    __shared__ double sd[256];
    sd[threadIdx.x] = (double)num[r] / (double)Z[r];
    __syncthreads();
    for (int st = 128; st > 0; st >>= 1) {
        if (threadIdx.x < st) sd[threadIdx.x] += sd[threadIdx.x + st];
        __syncthreads();
    }
    if (threadIdx.x == 0) {
        part[blockIdx.x] = sd[0];
        __threadfence();
        unsigned old = atomicAdd(cnt, 1u);
        if (old == 31u) {                // last block folds
            __threadfence();
            double a = 0.0;
            for (int k = 0; k < 32; ++k) a += part[k];
            out[0] = (float)(a / 67108864.0);   // / B^2
        }
    }
}

// ---------------- host launcher -----------------------------------------
extern "C" void kernel_launch(void* const* d_in, const int* in_sizes, int n_in,
                              void* d_out, int out_size, void* d_ws, size_t ws_size,
                              hipStream_t stream) {
    const float* V = (const float*)d_in[0];   // [8192, 512] f32
    const float* E = (const float*)d_in[1];   // [8192, 64]  f32
    float* out = (float*)d_out;
    char* ws = (char*)d_ws;

    float*         n_   = (float*)(ws + 0);            // 32 KB
    float*         ne   = (float*)(ws + 32768);        // 32 KB
    float*         Z    = (float*)(ws + 65536);        // 32 KB (init 1 in k_prep)
    float*         num  = (float*)(ws + 98304);        // 32 KB (init 0 in k_prep)
    unsigned char* VF8  = (unsigned char*)(ws + 131072);// 4 MB fp8 V frags
    _Float16*      EFh  = (_Float16*)(ws + 4325376);   // 1 MB
    double*        part = (double*)(ws + 5373952);     // 256 B
    unsigned*      cnt  = (unsigned*)(ws + 5374208);   // 4 B

    k_prep<<<512, 256, 0, stream>>>(V, E, n_, ne, Z, num, VF8, EFh, cnt);
    k_mega<<<2080, 256, 0, stream>>>(VF8, EFh, ne, n_, Z, num);
    k_red <<<32, 256, 0, stream>>>(Z, num, part, cnt, out);
}